// Round 2
// baseline (1612.084 us; speedup 1.0000x reference)
//
#include <hip/hip_runtime.h>
#include <math.h>

#define NN 50000
#define NE 600000
#define DIM 128
#define NLAYERS 7
#define LDK 136           // padded LDS row stride in shorts (272B)
#define BN_EPS 1e-5f

typedef __attribute__((ext_vector_type(4))) float floatx4;
typedef __attribute__((ext_vector_type(8))) _Float16 half8;

__device__ __forceinline__ unsigned short f2h(float f) {
  _Float16 h = (_Float16)f;  // v_cvt_f16_f32, RTNE
  return __builtin_bit_cast(unsigned short, h);
}

__device__ __forceinline__ void atomicAddF(float* p, float v) {
  __hip_atomic_fetch_add(p, v, __ATOMIC_RELAXED, __HIP_MEMORY_SCOPE_AGENT);
}

// ---------------- CSR build ----------------

__global__ void hist_kernel(const int* __restrict__ ei, int* __restrict__ deg) {
  int e = blockIdx.x * 256 + threadIdx.x;
  if (e < NE) atomicAdd(&deg[ei[NE + e]], 1);
}

__global__ void scan_kernel(const int* __restrict__ deg, int* __restrict__ row,
                            int* __restrict__ cur) {
  __shared__ int sums[1024];
  const int CH = (NN + 1023) / 1024;  // 49
  int t = threadIdx.x;
  int base = t * CH;
  int s = 0;
  for (int i = 0; i < CH; i++) {
    int idx = base + i;
    if (idx < NN) s += deg[idx];
  }
  sums[t] = s;
  __syncthreads();
  for (int off = 1; off < 1024; off <<= 1) {
    int v = (t >= off) ? sums[t - off] : 0;
    __syncthreads();
    sums[t] += v;
    __syncthreads();
  }
  int run = (t > 0) ? sums[t - 1] : 0;
  for (int i = 0; i < CH; i++) {
    int idx = base + i;
    if (idx < NN) {
      row[idx] = run;
      cur[idx] = run;
      run += deg[idx];
    }
  }
  if (t == 1023) row[NN] = run;
}

__global__ void bucket_kernel(const int* __restrict__ ei, int* __restrict__ cur,
                              int* __restrict__ esrc) {
  int e = blockIdx.x * 256 + threadIdx.x;
  if (e < NE) {
    int d = ei[NE + e];
    int p = atomicAdd(&cur[d], 1);
    esrc[p] = ei[e];
  }
}

// ---------------- weight convert: fp32 [l][k][n] -> fp16 transposed [l*2+m][n][k] ----------------

__global__ void convw_kernel(const float* __restrict__ W1, const float* __restrict__ W2,
                             unsigned short* __restrict__ wb) {
  int i = blockIdx.x * 256 + threadIdx.x;  // 7*16384
  if (i >= NLAYERS * 16384) return;
  int l = i >> 14;
  int r = i & 16383;
  int n = r >> 7;
  int k = r & 127;
  wb[(size_t)(l * 2 + 0) * 16384 + n * 128 + k] = f2h(W1[(size_t)l * 16384 + k * 128 + n]);
  wb[(size_t)(l * 2 + 1) * 16384 + n * 128 + k] = f2h(W2[(size_t)l * 16384 + k * 128 + n]);
}

// ---------------- gather: agg[n] = sum_{e in CSR[n]} x[esrc[e]] ----------------

__global__ __launch_bounds__(256) void gather_kernel(
    const float* __restrict__ x, const int* __restrict__ esrc,
    const int* __restrict__ row, float* __restrict__ agg) {
  int w = (blockIdx.x * 256 + threadIdx.x) >> 6;  // one wave per node
  int lane = threadIdx.x & 63;
  if (w >= NN) return;
  int s0 = row[w], s1 = row[w + 1];
  float ax = 0.f, ay = 0.f;
  int e = s0;
  for (; e + 1 < s1; e += 2) {
    int sA = esrc[e], sB = esrc[e + 1];
    const float2 vA = *(const float2*)(x + (size_t)sA * DIM + lane * 2);
    const float2 vB = *(const float2*)(x + (size_t)sB * DIM + lane * 2);
    ax += vA.x + vB.x;
    ay += vA.y + vB.y;
  }
  if (e < s1) {
    int sA = esrc[e];
    const float2 vA = *(const float2*)(x + (size_t)sA * DIM + lane * 2);
    ax += vA.x;
    ay += vA.y;
  }
  float2 o;
  o.x = ax; o.y = ay;
  *(float2*)(agg + (size_t)w * DIM + lane * 2) = o;
}

// ---------------- fused MLP: act = act_fn((relu((x+agg)@W1+b1))@W2+b2), + BN partial stats ----------------

__global__ __launch_bounds__(256) void mlp_kernel(
    const float* __restrict__ xin, const float* __restrict__ agg,
    const unsigned short* __restrict__ wb,  // [2][128][128] fp16, transposed [n][k]
    const float* __restrict__ b1, const float* __restrict__ b2,
    float* __restrict__ act, float* __restrict__ bn, int mode) {
  __shared__ unsigned short hS[64 * LDK];   // h tile, later reused for T
  __shared__ unsigned short wS[128 * LDK];  // W1, later W2
  int tid = threadIdx.x;
  int row0 = blockIdx.x * 64;

  // stage h = x + agg -> fp16 LDS (coalesced: 32 float4 per row)
  for (int idx = tid; idx < 64 * 32; idx += 256) {
    int r = idx >> 5;
    int c = (idx & 31) * 4;
    unsigned int p0 = 0, p1 = 0;
    if (row0 + r < NN) {
      size_t g = (size_t)(row0 + r) * DIM + c;
      float4 xv = *(const float4*)(xin + g);
      float4 av = *(const float4*)(agg + g);
      float hx = xv.x + av.x, hy = xv.y + av.y, hz = xv.z + av.z, hw = xv.w + av.w;
      p0 = (unsigned int)f2h(hx) | ((unsigned int)f2h(hy) << 16);
      p1 = (unsigned int)f2h(hz) | ((unsigned int)f2h(hw) << 16);
    }
    uint2 pk; pk.x = p0; pk.y = p1;
    *(uint2*)&hS[r * LDK + c] = pk;
  }
  // stage W1 (fp16, [n][k] contiguous) -> LDS with padding
  for (int q = tid; q < 2048; q += 256) {
    int rw = q >> 4;
    int c8 = (q & 15) * 8;
    *(uint4*)&wS[rw * LDK + c8] = *(const uint4*)(wb + rw * 128 + c8);
  }
  __syncthreads();

  int lane = tid & 63;
  int wav = tid >> 6;
  int quad = lane >> 4;
  int lm = lane & 15;
  int mrow = wav * 16 + lm;

  floatx4 acc[8];
  // GEMM1: T = relu(h@W1 + b1)
  #pragma unroll
  for (int nt = 0; nt < 8; nt++) {
    floatx4 c = {0.f, 0.f, 0.f, 0.f};
    #pragma unroll
    for (int ks = 0; ks < 4; ks++) {
      half8 af = *(half8*)&hS[mrow * LDK + ks * 32 + quad * 8];
      half8 bf = *(half8*)&wS[(nt * 16 + lm) * LDK + ks * 32 + quad * 8];
      c = __builtin_amdgcn_mfma_f32_16x16x32_f16(af, bf, c, 0, 0, 0);
    }
    acc[nt] = c;
  }
  // write T over hS (each wave touches only its own 16 rows; barrier below)
  #pragma unroll
  for (int nt = 0; nt < 8; nt++) {
    float bv = b1[nt * 16 + lm];
    #pragma unroll
    for (int rg = 0; rg < 4; rg++) {
      float v = acc[nt][rg] + bv;
      v = v > 0.f ? v : 0.f;
      hS[(wav * 16 + quad * 4 + rg) * LDK + nt * 16 + lm] = f2h(v);
    }
  }
  __syncthreads();
  // stage W2
  for (int q = tid; q < 2048; q += 256) {
    int rw = q >> 4;
    int c8 = (q & 15) * 8;
    *(uint4*)&wS[rw * LDK + c8] = *(const uint4*)(wb + 16384 + rw * 128 + c8);
  }
  __syncthreads();

  bool wvalid = (row0 + wav * 16) < NN;  // NN % 16 == 0, validity is wave-uniform
  #pragma unroll
  for (int nt = 0; nt < 8; nt++) {
    floatx4 c = {0.f, 0.f, 0.f, 0.f};
    #pragma unroll
    for (int ks = 0; ks < 4; ks++) {
      half8 af = *(half8*)&hS[mrow * LDK + ks * 32 + quad * 8];
      half8 bf = *(half8*)&wS[(nt * 16 + lm) * LDK + ks * 32 + quad * 8];
      c = __builtin_amdgcn_mfma_f32_16x16x32_f16(af, bf, c, 0, 0, 0);
    }
    float bv = b2[nt * 16 + lm];
    float s = 0.f, sq = 0.f;
    #pragma unroll
    for (int rg = 0; rg < 4; rg++) {
      float v = c[rg] + bv;
      v = mode ? tanhf(v) : (v > 0.f ? v : 0.f);
      if (wvalid)
        act[(size_t)(row0 + wav * 16 + quad * 4 + rg) * DIM + nt * 16 + lm] = v;
      s += v;
      sq += v * v;
    }
    // reduce 4 quads -> column sums over this wave's 16 rows
    s += __shfl_xor(s, 16);
    s += __shfl_xor(s, 32);
    sq += __shfl_xor(sq, 16);
    sq += __shfl_xor(sq, 32);
    if (wvalid && quad == 0) {
      atomicAddF(&bn[nt * 16 + lm], s);
      atomicAddF(&bn[128 + nt * 16 + lm], sq);
    }
  }
}

// ---------------- BN normalize (scale/shift recomputed per thread from bn sums) ----------------

__global__ __launch_bounds__(256) void norm_kernel(
    const float* __restrict__ a, const float* __restrict__ bn,
    const float* __restrict__ gamma, const float* __restrict__ beta,
    float* __restrict__ o) {
  int i = blockIdx.x * 256 + threadIdx.x;  // 1.6M threads, exact
  int f = (i & 31) * 4;
  const float inv = 1.f / (float)NN;
  float4 v = ((const float4*)a)[i];
  float r[4] = {v.x, v.y, v.z, v.w};
  #pragma unroll
  for (int j = 0; j < 4; j++) {
    float mean = bn[f + j] * inv;
    float var = bn[128 + f + j] * inv - mean * mean;
    float sc = gamma[f + j] * rsqrtf(var + BN_EPS);
    r[j] = (r[j] - mean) * sc + beta[f + j];
  }
  float4 ov; ov.x = r[0]; ov.y = r[1]; ov.z = r[2]; ov.w = r[3];
  ((float4*)o)[i] = ov;
}

// ---------------- host ----------------

extern "C" void kernel_launch(void* const* d_in, const int* in_sizes, int n_in,
                              void* d_out, int out_size, void* d_ws, size_t ws_size,
                              hipStream_t stream) {
  const float* x_in = (const float*)d_in[0];
  const int* ei = (const int*)d_in[1];
  const float* W1g = (const float*)d_in[3];
  const float* b1g = (const float*)d_in[4];
  const float* W2g = (const float*)d_in[5];
  const float* b2g = (const float*)d_in[6];
  const float* gg = (const float*)d_in[7];
  const float* bg = (const float*)d_in[8];
  float* out = (float*)d_out;

  char* ws = (char*)d_ws;
  const size_t OFF_AGG = 0;                  // 25,600,000 B
  const size_t OFF_X = 25600000;             // 25,600,000 B
  const size_t OFF_A = 51200000;             // 25,600,000 B
  const size_t OFF_WB = 76800000;            // 458,752 B
  const size_t OFF_BN = 77258752;            // 1,024 B
  const size_t OFF_DEG = 77259776;           // 200,000 B
  const size_t OFF_ROW = 77459776;           // 200,004 B
  const size_t OFF_CUR = 77659780;           // 200,000 B
  const size_t OFF_ESR = 77859780;           // 2,400,000 B

  float* agg = (float*)(ws + OFF_AGG);
  float* X = (float*)(ws + OFF_X);
  float* A = (float*)(ws + OFF_A);
  unsigned short* wb = (unsigned short*)(ws + OFF_WB);
  float* bn = (float*)(ws + OFF_BN);
  int* deg = (int*)(ws + OFF_DEG);
  int* rowp = (int*)(ws + OFF_ROW);
  int* cur = (int*)(ws + OFF_CUR);
  int* esrc = (int*)(ws + OFF_ESR);

  // CSR build (graph is static per call; built once)
  hipMemsetAsync(deg, 0, NN * sizeof(int), stream);
  hist_kernel<<<(NE + 255) / 256, 256, 0, stream>>>(ei, deg);
  scan_kernel<<<1, 1024, 0, stream>>>(deg, rowp, cur);
  bucket_kernel<<<(NE + 255) / 256, 256, 0, stream>>>(ei, cur, esrc);
  convw_kernel<<<(NLAYERS * 16384 + 255) / 256, 256, 0, stream>>>(W1g, W2g, wb);

  const int GB = (NN + 63) / 64;  // 782 mlp blocks
  // layers 0..2 (chained; act written in-place to X, normalized in-place)
  for (int i = 0; i < 3; i++) {
    const float* xi = (i == 0) ? x_in : X;
    gather_kernel<<<(NN * 64 + 255) / 256, 256, 0, stream>>>(xi, esrc, rowp, agg);
    hipMemsetAsync(bn, 0, 256 * sizeof(float), stream);
    mlp_kernel<<<GB, 256, 0, stream>>>(xi, agg, wb + (size_t)i * 2 * 16384,
                                       b1g + i * 128, b2g + i * 128, X, bn, 0);
    norm_kernel<<<NN * DIM / 4 / 256, 256, 0, stream>>>(X, bn, gg + i * 128,
                                                        bg + i * 128, X);
  }
  // layers 3..6 share input X -> one gather
  gather_kernel<<<(NN * 64 + 255) / 256, 256, 0, stream>>>(X, esrc, rowp, agg);
  for (int k = 3; k < 7; k++) {
    hipMemsetAsync(bn, 0, 256 * sizeof(float), stream);
    mlp_kernel<<<GB, 256, 0, stream>>>(X, agg, wb + (size_t)k * 2 * 16384,
                                       b1g + k * 128, b2g + k * 128, A, bn, 1);
    norm_kernel<<<NN * DIM / 4 / 256, 256, 0, stream>>>(
        A, bn, gg + k * 128, bg + k * 128, out + (size_t)(k - 3) * NN * DIM);
  }
}

// Round 3
// 765.142 us; speedup vs baseline: 2.1069x; 2.1069x over previous
//
#include <hip/hip_runtime.h>
#include <math.h>

#define NN 50000
#define NE 600000
#define DIM 128
#define NLAYERS 7
#define LDK 136           // padded LDS row stride in shorts (272B)
#define BN_EPS 1e-5f
#define GB 782            // mlp blocks per layer (ceil(50000/64))
#define PART_SLOT 200192  // GB*256 floats per layer slot

typedef __attribute__((ext_vector_type(4))) float floatx4;
typedef __attribute__((ext_vector_type(8))) _Float16 half8;

__device__ __forceinline__ unsigned short f2h(float f) {
  _Float16 h = (_Float16)f;  // v_cvt_f16_f32, RTNE
  return __builtin_bit_cast(unsigned short, h);
}

// ---------------- CSR build ----------------

__global__ void hist_kernel(const int* __restrict__ ei, int* __restrict__ deg) {
  int e = blockIdx.x * 256 + threadIdx.x;
  if (e < NE) atomicAdd(&deg[ei[NE + e]], 1);
}

__global__ void scan_kernel(const int* __restrict__ deg, int* __restrict__ row,
                            int* __restrict__ cur) {
  __shared__ int sums[1024];
  const int CH = (NN + 1023) / 1024;  // 49
  int t = threadIdx.x;
  int base = t * CH;
  int s = 0;
  for (int i = 0; i < CH; i++) {
    int idx = base + i;
    if (idx < NN) s += deg[idx];
  }
  sums[t] = s;
  __syncthreads();
  for (int off = 1; off < 1024; off <<= 1) {
    int v = (t >= off) ? sums[t - off] : 0;
    __syncthreads();
    sums[t] += v;
    __syncthreads();
  }
  int run = (t > 0) ? sums[t - 1] : 0;
  for (int i = 0; i < CH; i++) {
    int idx = base + i;
    if (idx < NN) {
      row[idx] = run;
      cur[idx] = run;
      run += deg[idx];
    }
  }
  if (t == 1023) row[NN] = run;
}

__global__ void bucket_kernel(const int* __restrict__ ei, int* __restrict__ cur,
                              int* __restrict__ esrc) {
  int e = blockIdx.x * 256 + threadIdx.x;
  if (e < NE) {
    int d = ei[NE + e];
    int p = atomicAdd(&cur[d], 1);
    esrc[p] = ei[e];
  }
}

// ---------------- weight convert: fp32 [l][k][n] -> fp16 transposed [l*2+m][n][k] ----------------

__global__ void convw_kernel(const float* __restrict__ W1, const float* __restrict__ W2,
                             unsigned short* __restrict__ wb) {
  int i = blockIdx.x * 256 + threadIdx.x;  // 7*16384
  if (i >= NLAYERS * 16384) return;
  int l = i >> 14;
  int r = i & 16383;
  int n = r >> 7;
  int k = r & 127;
  wb[(size_t)(l * 2 + 0) * 16384 + n * 128 + k] = f2h(W1[(size_t)l * 16384 + k * 128 + n]);
  wb[(size_t)(l * 2 + 1) * 16384 + n * 128 + k] = f2h(W2[(size_t)l * 16384 + k * 128 + n]);
}

// ---------------- gather: agg[n] = sum_{e in CSR[n]} x[esrc[e]] ----------------

__global__ __launch_bounds__(256) void gather_kernel(
    const float* __restrict__ x, const int* __restrict__ esrc,
    const int* __restrict__ row, float* __restrict__ agg) {
  int w = (blockIdx.x * 256 + threadIdx.x) >> 6;  // one wave per node
  int lane = threadIdx.x & 63;
  if (w >= NN) return;
  int s0 = row[w], s1 = row[w + 1];
  float ax = 0.f, ay = 0.f;
  int e = s0;
  for (; e + 1 < s1; e += 2) {
    int sA = esrc[e], sB = esrc[e + 1];
    const float2 vA = *(const float2*)(x + (size_t)sA * DIM + lane * 2);
    const float2 vB = *(const float2*)(x + (size_t)sB * DIM + lane * 2);
    ax += vA.x + vB.x;
    ay += vA.y + vB.y;
  }
  if (e < s1) {
    int sA = esrc[e];
    const float2 vA = *(const float2*)(x + (size_t)sA * DIM + lane * 2);
    ax += vA.x;
    ay += vA.y;
  }
  float2 o;
  o.x = ax; o.y = ay;
  *(float2*)(agg + (size_t)w * DIM + lane * 2) = o;
}

// ---------------- fused MLP: act = act_fn((relu((x+agg)@W1+b1))@W2+b2) + BN partials ----------------
// grid.y indexes layers layer0+by (they share xin/agg); partials go to part[slot by].

__global__ __launch_bounds__(256) void mlp_kernel(
    const float* __restrict__ xin, const float* __restrict__ agg,
    const unsigned short* __restrict__ wbg,
    const float* __restrict__ b1g, const float* __restrict__ b2g,
    float* __restrict__ actBase, size_t actStride,
    float* __restrict__ partBase, int layer0) {
  __shared__ unsigned short hS[64 * LDK];   // h tile, later reused for T
  __shared__ unsigned short wS[128 * LDK];  // W1, later W2
  __shared__ float redS[1024];              // [4 waves][256 stat cols]
  int tid = threadIdx.x;
  int row0 = blockIdx.x * 64;
  int layer = layer0 + blockIdx.y;
  const unsigned short* wb = wbg + (size_t)layer * 2 * 16384;
  const float* b1 = b1g + layer * 128;
  const float* b2 = b2g + layer * 128;
  float* act = actBase + (size_t)blockIdx.y * actStride;
  float* part = partBase + (size_t)blockIdx.y * PART_SLOT;
  int mode = (layer >= 3);

  // stage h = x + agg -> fp16 LDS (coalesced: 32 float4 per row)
  for (int idx = tid; idx < 64 * 32; idx += 256) {
    int r = idx >> 5;
    int c = (idx & 31) * 4;
    unsigned int p0 = 0, p1 = 0;
    if (row0 + r < NN) {
      size_t g = (size_t)(row0 + r) * DIM + c;
      float4 xv = *(const float4*)(xin + g);
      float4 av = *(const float4*)(agg + g);
      float hx = xv.x + av.x, hy = xv.y + av.y, hz = xv.z + av.z, hw = xv.w + av.w;
      p0 = (unsigned int)f2h(hx) | ((unsigned int)f2h(hy) << 16);
      p1 = (unsigned int)f2h(hz) | ((unsigned int)f2h(hw) << 16);
    }
    uint2 pk; pk.x = p0; pk.y = p1;
    *(uint2*)&hS[r * LDK + c] = pk;
  }
  // stage W1 (fp16, [n][k] contiguous) -> LDS with padding
  for (int q = tid; q < 2048; q += 256) {
    int rw = q >> 4;
    int c8 = (q & 15) * 8;
    *(uint4*)&wS[rw * LDK + c8] = *(const uint4*)(wb + rw * 128 + c8);
  }
  __syncthreads();

  int lane = tid & 63;
  int wav = tid >> 6;
  int quad = lane >> 4;
  int lm = lane & 15;
  int mrow = wav * 16 + lm;

  floatx4 acc[8];
  // GEMM1: T = relu(h@W1 + b1)
  #pragma unroll
  for (int nt = 0; nt < 8; nt++) {
    floatx4 c = {0.f, 0.f, 0.f, 0.f};
    #pragma unroll
    for (int ks = 0; ks < 4; ks++) {
      half8 af = *(half8*)&hS[mrow * LDK + ks * 32 + quad * 8];
      half8 bf = *(half8*)&wS[(nt * 16 + lm) * LDK + ks * 32 + quad * 8];
      c = __builtin_amdgcn_mfma_f32_16x16x32_f16(af, bf, c, 0, 0, 0);
    }
    acc[nt] = c;
  }
  // write T over hS (each wave touches only its own 16 rows; barrier below)
  #pragma unroll
  for (int nt = 0; nt < 8; nt++) {
    float bv = b1[nt * 16 + lm];
    #pragma unroll
    for (int rg = 0; rg < 4; rg++) {
      float v = acc[nt][rg] + bv;
      v = v > 0.f ? v : 0.f;
      hS[(wav * 16 + quad * 4 + rg) * LDK + nt * 16 + lm] = f2h(v);
    }
  }
  __syncthreads();
  // stage W2
  for (int q = tid; q < 2048; q += 256) {
    int rw = q >> 4;
    int c8 = (q & 15) * 8;
    *(uint4*)&wS[rw * LDK + c8] = *(const uint4*)(wb + 16384 + rw * 128 + c8);
  }
  __syncthreads();

  bool wvalid = (row0 + wav * 16) < NN;  // validity is wave-uniform (16 | NN)
  #pragma unroll
  for (int nt = 0; nt < 8; nt++) {
    floatx4 c = {0.f, 0.f, 0.f, 0.f};
    #pragma unroll
    for (int ks = 0; ks < 4; ks++) {
      half8 af = *(half8*)&hS[mrow * LDK + ks * 32 + quad * 8];
      half8 bf = *(half8*)&wS[(nt * 16 + lm) * LDK + ks * 32 + quad * 8];
      c = __builtin_amdgcn_mfma_f32_16x16x32_f16(af, bf, c, 0, 0, 0);
    }
    float bv = b2[nt * 16 + lm];
    float s = 0.f, sq = 0.f;
    #pragma unroll
    for (int rg = 0; rg < 4; rg++) {
      float v = c[rg] + bv;
      v = mode ? tanhf(v) : (v > 0.f ? v : 0.f);
      if (wvalid)
        act[(size_t)(row0 + wav * 16 + quad * 4 + rg) * DIM + nt * 16 + lm] = v;
      s += v;
      sq += v * v;
    }
    // reduce 4 quads -> column sums over this wave's 16 rows (all lanes get total)
    s += __shfl_xor(s, 16);
    s += __shfl_xor(s, 32);
    sq += __shfl_xor(sq, 16);
    sq += __shfl_xor(sq, 32);
    if (quad == 0) {
      redS[wav * 256 + nt * 16 + lm] = wvalid ? s : 0.f;
      redS[wav * 256 + 128 + nt * 16 + lm] = wvalid ? sq : 0.f;
    }
  }
  __syncthreads();
  // cross-wave reduce -> one coalesced 1KB partial store per block (no atomics)
  float v = redS[tid] + redS[256 + tid] + redS[512 + tid] + redS[768 + tid];
  part[(size_t)blockIdx.x * 256 + tid] = v;
}

// ---------------- fold per-block partials -> bn[layer][256] ----------------

__global__ __launch_bounds__(256) void reduce_kernel(const float* __restrict__ part,
                                                     float* __restrict__ bn) {
  int c = blockIdx.x;  // stat column 0..255
  int t = threadIdx.x;
  const float* p = part + (size_t)blockIdx.y * PART_SLOT + c;
  float s = 0.f;
  for (int b = t; b < GB; b += 256) s += p[(size_t)b * 256];
  #pragma unroll
  for (int off = 1; off < 64; off <<= 1) s += __shfl_xor(s, off);
  __shared__ float wsum[4];
  if ((t & 63) == 0) wsum[t >> 6] = s;
  __syncthreads();
  if (t == 0) bn[blockIdx.y * 256 + c] = wsum[0] + wsum[1] + wsum[2] + wsum[3];
}

// ---------------- BN normalize ----------------

__global__ __launch_bounds__(256) void norm_kernel(
    const float* __restrict__ aBase, size_t aStride, const float* __restrict__ bnAll,
    const float* __restrict__ gammaAll, const float* __restrict__ betaAll,
    float* __restrict__ oBase, size_t oStride, int layer0) {
  int layer = layer0 + blockIdx.y;
  const float* a = aBase + (size_t)blockIdx.y * aStride;
  const float* bn = bnAll + blockIdx.y * 256;
  const float* gamma = gammaAll + layer * 128;
  const float* beta = betaAll + layer * 128;
  float* o = oBase + (size_t)blockIdx.y * oStride;
  int i = blockIdx.x * 256 + threadIdx.x;  // 1.6M threads per layer, exact
  int f = (i & 31) * 4;
  const float inv = 1.f / (float)NN;
  float4 v = ((const float4*)a)[i];
  float r[4] = {v.x, v.y, v.z, v.w};
  #pragma unroll
  for (int j = 0; j < 4; j++) {
    float mean = bn[f + j] * inv;
    float var = bn[128 + f + j] * inv - mean * mean;
    float sc = gamma[f + j] * rsqrtf(var + BN_EPS);
    r[j] = (r[j] - mean) * sc + beta[f + j];
  }
  float4 ov; ov.x = r[0]; ov.y = r[1]; ov.z = r[2]; ov.w = r[3];
  ((float4*)o)[i] = ov;
}

// ---------------- host ----------------

extern "C" void kernel_launch(void* const* d_in, const int* in_sizes, int n_in,
                              void* d_out, int out_size, void* d_ws, size_t ws_size,
                              hipStream_t stream) {
  const float* x_in = (const float*)d_in[0];
  const int* ei = (const int*)d_in[1];
  const float* W1g = (const float*)d_in[3];
  const float* b1g = (const float*)d_in[4];
  const float* W2g = (const float*)d_in[5];
  const float* b2g = (const float*)d_in[6];
  const float* gg = (const float*)d_in[7];
  const float* bg = (const float*)d_in[8];
  float* out = (float*)d_out;

  char* ws = (char*)d_ws;
  const size_t OFF_AGG = 0;                  // 25,600,000 B
  const size_t OFF_X = 25600000;             // 25,600,000 B
  const size_t OFF_WB = 51200000;            // 458,752 B
  const size_t OFF_BN = 51658752;            // 4,096 B (4 layer slots)
  const size_t OFF_DEG = 51662848;           // 200,000 B
  const size_t OFF_ROW = 51862848;           // 200,004 B
  const size_t OFF_CUR = 52062852;           // 200,000 B
  const size_t OFF_ESR = 52262852;           // 2,400,000 B
  const size_t OFF_PART = 54662852;          // 4 * PART_SLOT * 4 B = 3,203,072 B

  float* agg = (float*)(ws + OFF_AGG);
  float* X = (float*)(ws + OFF_X);
  unsigned short* wb = (unsigned short*)(ws + OFF_WB);
  float* bn = (float*)(ws + OFF_BN);
  int* deg = (int*)(ws + OFF_DEG);
  int* rowp = (int*)(ws + OFF_ROW);
  int* cur = (int*)(ws + OFF_CUR);
  int* esrc = (int*)(ws + OFF_ESR);
  float* part = (float*)(ws + OFF_PART);

  // CSR build (graph is static per call; built once)
  hipMemsetAsync(deg, 0, NN * sizeof(int), stream);
  hist_kernel<<<(NE + 255) / 256, 256, 0, stream>>>(ei, deg);
  scan_kernel<<<1, 1024, 0, stream>>>(deg, rowp, cur);
  bucket_kernel<<<(NE + 255) / 256, 256, 0, stream>>>(ei, cur, esrc);
  convw_kernel<<<(NLAYERS * 16384 + 255) / 256, 256, 0, stream>>>(W1g, W2g, wb);

  // layers 0..2 (chained; act written in-place to X, normalized in-place)
  for (int i = 0; i < 3; i++) {
    const float* xi = (i == 0) ? x_in : X;
    gather_kernel<<<(NN * 64 + 255) / 256, 256, 0, stream>>>(xi, esrc, rowp, agg);
    mlp_kernel<<<dim3(GB, 1), 256, 0, stream>>>(xi, agg, wb, b1g, b2g, X, 0, part, i);
    reduce_kernel<<<dim3(256, 1), 256, 0, stream>>>(part, bn);
    norm_kernel<<<dim3(NN * DIM / 4 / 256, 1), 256, 0, stream>>>(X, 0, bn, gg, bg, X, 0, i);
  }
  // layers 3..6 share input X -> one gather, batched mlp (grid.y=4) writing into out
  gather_kernel<<<(NN * 64 + 255) / 256, 256, 0, stream>>>(X, esrc, rowp, agg);
  mlp_kernel<<<dim3(GB, 4), 256, 0, stream>>>(X, agg, wb, b1g, b2g, out,
                                              (size_t)NN * DIM, part, 3);
  reduce_kernel<<<dim3(256, 4), 256, 0, stream>>>(part, bn);
  norm_kernel<<<dim3(NN * DIM / 4 / 256, 4), 256, 0, stream>>>(
      out, (size_t)NN * DIM, bn, gg, bg, out, (size_t)NN * DIM, 3);
}

// Round 4
// 601.335 us; speedup vs baseline: 2.6808x; 1.2724x over previous
//
#include <hip/hip_runtime.h>
#include <math.h>

#define NN 50000
#define NE 600000
#define DIM 128
#define NLAYERS 7
#define LDK 136           // padded LDS row stride in shorts (272B)
#define BN_EPS 1e-5f
#define GB 782            // mlp blocks per layer (ceil(50000/64))
#define PART_SLOT 200192  // GB*256 floats per layer slot

typedef __attribute__((ext_vector_type(4))) float floatx4;
typedef __attribute__((ext_vector_type(8))) _Float16 half8;

__device__ __forceinline__ unsigned short f2h(float f) {
  _Float16 h = (_Float16)f;  // v_cvt_f16_f32, RTNE
  return __builtin_bit_cast(unsigned short, h);
}

// ---------------- CSR build ----------------

__global__ void hist_kernel(const int* __restrict__ ei, int* __restrict__ deg) {
  int e = blockIdx.x * 256 + threadIdx.x;
  if (e < NE) atomicAdd(&deg[ei[NE + e]], 1);
}

// hierarchical scan: part (49 blocks x 1024 elems) -> top (1 wave) -> apply
__global__ __launch_bounds__(256) void scan_part(const int* __restrict__ deg,
                                                 int* __restrict__ rowl,
                                                 int* __restrict__ bsum) {
  int b = blockIdx.x, t = threadIdx.x;
  int base = b * 1024 + t * 4;
  int d[4];
  #pragma unroll
  for (int j = 0; j < 4; j++) d[j] = (base + j < NN) ? deg[base + j] : 0;
  int s = d[0] + d[1] + d[2] + d[3];
  int lane = t & 63;
  int incl = s;
  #pragma unroll
  for (int off = 1; off < 64; off <<= 1) {
    int n = __shfl_up(incl, off);
    if (lane >= off) incl += n;
  }
  __shared__ int wtot[4];
  if (lane == 63) wtot[t >> 6] = incl;
  __syncthreads();
  int woff = 0;
  for (int w = 0; w < (t >> 6); w++) woff += wtot[w];
  int run = woff + incl - s;
  #pragma unroll
  for (int j = 0; j < 4; j++) {
    if (base + j < NN) rowl[base + j] = run;
    run += d[j];
  }
  if (t == 255) bsum[b] = woff + incl;
}

__global__ void scan_top(const int* __restrict__ bsum, int* __restrict__ boff,
                         int* __restrict__ row) {
  int t = threadIdx.x;  // 64 threads, one wave
  int v = (t < 49) ? bsum[t] : 0;
  int incl = v;
  #pragma unroll
  for (int off = 1; off < 64; off <<= 1) {
    int n = __shfl_up(incl, off);
    if (t >= off) incl += n;
  }
  if (t < 49) boff[t] = incl - v;
  if (t == 48) row[NN] = incl;  // grand total = NE
}

__global__ __launch_bounds__(256) void scan_apply(const int* __restrict__ rowl,
                                                  const int* __restrict__ boff,
                                                  int* __restrict__ row,
                                                  int* __restrict__ cur) {
  int i = blockIdx.x * 256 + threadIdx.x;
  if (i < NN) {
    int r = rowl[i] + boff[i >> 10];
    row[i] = r;
    cur[i] = r;
  }
}

__global__ void bucket_kernel(const int* __restrict__ ei, int* __restrict__ cur,
                              int* __restrict__ esrc) {
  int e = blockIdx.x * 256 + threadIdx.x;
  if (e < NE) {
    int d = ei[NE + e];
    int p = atomicAdd(&cur[d], 1);
    esrc[p] = ei[e];
  }
}

// ---------------- weight convert: fp32 [l][k][n] -> fp16 transposed [l*2+m][n][k] ----------------

__global__ void convw_kernel(const float* __restrict__ W1, const float* __restrict__ W2,
                             unsigned short* __restrict__ wb) {
  int i = blockIdx.x * 256 + threadIdx.x;  // 7*16384
  if (i >= NLAYERS * 16384) return;
  int l = i >> 14;
  int r = i & 16383;
  int n = r >> 7;
  int k = r & 127;
  wb[(size_t)(l * 2 + 0) * 16384 + n * 128 + k] = f2h(W1[(size_t)l * 16384 + k * 128 + n]);
  wb[(size_t)(l * 2 + 1) * 16384 + n * 128 + k] = f2h(W2[(size_t)l * 16384 + k * 128 + n]);
}

// ---------------- gather: agg[n] = sum_{e in CSR[n]} x[esrc[e]] ----------------

__global__ __launch_bounds__(256) void gather_kernel(
    const float* __restrict__ x, const int* __restrict__ esrc,
    const int* __restrict__ row, float* __restrict__ agg) {
  int w = (blockIdx.x * 256 + threadIdx.x) >> 6;  // one wave per node
  int lane = threadIdx.x & 63;
  if (w >= NN) return;
  int s0 = row[w], s1 = row[w + 1];
  float ax = 0.f, ay = 0.f;
  int e = s0;
  for (; e + 1 < s1; e += 2) {
    int sA = esrc[e], sB = esrc[e + 1];
    const float2 vA = *(const float2*)(x + (size_t)sA * DIM + lane * 2);
    const float2 vB = *(const float2*)(x + (size_t)sB * DIM + lane * 2);
    ax += vA.x + vB.x;
    ay += vA.y + vB.y;
  }
  if (e < s1) {
    int sA = esrc[e];
    const float2 vA = *(const float2*)(x + (size_t)sA * DIM + lane * 2);
    ax += vA.x;
    ay += vA.y;
  }
  float2 o;
  o.x = ax; o.y = ay;
  *(float2*)(agg + (size_t)w * DIM + lane * 2) = o;
}

// ---------------- fused MLP with folded-in BN of the PREVIOUS layer ----------------
// h = sc[c]*(x_raw + agg_raw) + (1+deg[r])*sh[c]   (sc=1, sh=0 when hasPrev=0)
// act_raw = act_fn(relu(h@W1+b1)@W2+b2); BN partial sums -> part.

__global__ __launch_bounds__(256) void mlp_kernel(
    const float* __restrict__ xin, const float* __restrict__ agg,
    const unsigned short* __restrict__ wbg,
    const float* __restrict__ b1g, const float* __restrict__ b2g,
    float* __restrict__ actBase, size_t actStride,
    float* __restrict__ partBase, int layer0,
    const float* __restrict__ bnPrev, const float* __restrict__ gPrev,
    const float* __restrict__ btPrev, const int* __restrict__ deg, int hasPrev) {
  __shared__ unsigned short hS[64 * LDK];   // h tile, later T, finally stat scratch
  __shared__ unsigned short wS[128 * LDK];  // W1, later W2
  __shared__ float scshS[256];              // sc[0..127], sh[128..255]
  int tid = threadIdx.x;
  int row0 = blockIdx.x * 64;
  int layer = layer0 + blockIdx.y;
  const unsigned short* wb = wbg + (size_t)layer * 2 * 16384;
  const float* b1 = b1g + layer * 128;
  const float* b2 = b2g + layer * 128;
  float* act = actBase + (size_t)blockIdx.y * actStride;
  float* part = partBase + (size_t)blockIdx.y * PART_SLOT;
  int mode = (layer >= 3);

  if (tid < 128) {
    float sc = 1.f, sh = 0.f;
    if (hasPrev) {
      const float inv = 1.f / (float)NN;
      float mean = bnPrev[tid] * inv;
      float var = bnPrev[128 + tid] * inv - mean * mean;
      sc = gPrev[tid] * rsqrtf(var + BN_EPS);
      sh = btPrev[tid] - mean * sc;
    }
    scshS[tid] = sc;
    scshS[128 + tid] = sh;
  }
  __syncthreads();

  // stage h -> fp16 LDS (coalesced: 32 float4 per row)
  for (int idx = tid; idx < 64 * 32; idx += 256) {
    int r = idx >> 5;
    int c = (idx & 31) * 4;
    unsigned int p0 = 0, p1 = 0;
    if (row0 + r < NN) {
      size_t g = (size_t)(row0 + r) * DIM + c;
      float4 xv = *(const float4*)(xin + g);
      float4 av = *(const float4*)(agg + g);
      float dr = 1.f + (float)deg[row0 + r];
      float h0 = scshS[c + 0] * (xv.x + av.x) + dr * scshS[128 + c + 0];
      float h1 = scshS[c + 1] * (xv.y + av.y) + dr * scshS[128 + c + 1];
      float h2 = scshS[c + 2] * (xv.z + av.z) + dr * scshS[128 + c + 2];
      float h3 = scshS[c + 3] * (xv.w + av.w) + dr * scshS[128 + c + 3];
      p0 = (unsigned int)f2h(h0) | ((unsigned int)f2h(h1) << 16);
      p1 = (unsigned int)f2h(h2) | ((unsigned int)f2h(h3) << 16);
    }
    uint2 pk; pk.x = p0; pk.y = p1;
    *(uint2*)&hS[r * LDK + c] = pk;
  }
  // stage W1 (fp16, [n][k] contiguous) -> LDS with padding
  for (int q = tid; q < 2048; q += 256) {
    int rw = q >> 4;
    int c8 = (q & 15) * 8;
    *(uint4*)&wS[rw * LDK + c8] = *(const uint4*)(wb + rw * 128 + c8);
  }
  __syncthreads();

  int lane = tid & 63;
  int wav = tid >> 6;
  int quad = lane >> 4;
  int lm = lane & 15;
  int mrow = wav * 16 + lm;

  floatx4 acc[8];
  // GEMM1: T = relu(h@W1 + b1)
  #pragma unroll
  for (int nt = 0; nt < 8; nt++) {
    floatx4 c = {0.f, 0.f, 0.f, 0.f};
    #pragma unroll
    for (int ks = 0; ks < 4; ks++) {
      half8 af = *(half8*)&hS[mrow * LDK + ks * 32 + quad * 8];
      half8 bf = *(half8*)&wS[(nt * 16 + lm) * LDK + ks * 32 + quad * 8];
      c = __builtin_amdgcn_mfma_f32_16x16x32_f16(af, bf, c, 0, 0, 0);
    }
    acc[nt] = c;
  }
  // write T over hS (each wave touches only its own 16 rows; barrier below)
  #pragma unroll
  for (int nt = 0; nt < 8; nt++) {
    float bv = b1[nt * 16 + lm];
    #pragma unroll
    for (int rg = 0; rg < 4; rg++) {
      float v = acc[nt][rg] + bv;
      v = v > 0.f ? v : 0.f;
      hS[(wav * 16 + quad * 4 + rg) * LDK + nt * 16 + lm] = f2h(v);
    }
  }
  __syncthreads();
  // stage W2
  for (int q = tid; q < 2048; q += 256) {
    int rw = q >> 4;
    int c8 = (q & 15) * 8;
    *(uint4*)&wS[rw * LDK + c8] = *(const uint4*)(wb + 16384 + rw * 128 + c8);
  }
  __syncthreads();

  bool wvalid = (row0 + wav * 16) < NN;  // validity is wave-uniform (16 | NN)
  float sArr[8], sqArr[8];
  #pragma unroll
  for (int nt = 0; nt < 8; nt++) {
    floatx4 c = {0.f, 0.f, 0.f, 0.f};
    #pragma unroll
    for (int ks = 0; ks < 4; ks++) {
      half8 af = *(half8*)&hS[mrow * LDK + ks * 32 + quad * 8];
      half8 bf = *(half8*)&wS[(nt * 16 + lm) * LDK + ks * 32 + quad * 8];
      c = __builtin_amdgcn_mfma_f32_16x16x32_f16(af, bf, c, 0, 0, 0);
    }
    float bv = b2[nt * 16 + lm];
    float s = 0.f, sq = 0.f;
    #pragma unroll
    for (int rg = 0; rg < 4; rg++) {
      float v = c[rg] + bv;
      v = mode ? tanhf(v) : (v > 0.f ? v : 0.f);
      if (wvalid)
        act[(size_t)(row0 + wav * 16 + quad * 4 + rg) * DIM + nt * 16 + lm] = v;
      s += v;
      sq += v * v;
    }
    // reduce 4 quads -> column sums over this wave's 16 rows
    s += __shfl_xor(s, 16);
    s += __shfl_xor(s, 32);
    sq += __shfl_xor(sq, 16);
    sq += __shfl_xor(sq, 32);
    sArr[nt] = s;
    sqArr[nt] = sq;
  }
  __syncthreads();  // all hS reads done; reuse hS as float stat scratch
  float* redS = (float*)hS;  // [4 waves][256]
  if (quad == 0) {
    #pragma unroll
    for (int nt = 0; nt < 8; nt++) {
      redS[wav * 256 + nt * 16 + lm] = wvalid ? sArr[nt] : 0.f;
      redS[wav * 256 + 128 + nt * 16 + lm] = wvalid ? sqArr[nt] : 0.f;
    }
  }
  __syncthreads();
  // cross-wave reduce -> one coalesced 1KB partial store per block (no atomics)
  float v = redS[tid] + redS[256 + tid] + redS[512 + tid] + redS[768 + tid];
  part[(size_t)blockIdx.x * 256 + tid] = v;
}

// ---------------- fold per-block partials -> bn[256] per layer slot ----------------

__global__ __launch_bounds__(256) void reduce_kernel(const float* __restrict__ part,
                                                     float* __restrict__ bn) {
  int c = blockIdx.x;  // stat column 0..255
  int t = threadIdx.x;
  const float* p = part + (size_t)blockIdx.y * PART_SLOT + c;
  float s = 0.f;
  for (int b = t; b < GB; b += 256) s += p[(size_t)b * 256];
  #pragma unroll
  for (int off = 1; off < 64; off <<= 1) s += __shfl_xor(s, off);
  __shared__ float wsum[4];
  if ((t & 63) == 0) wsum[t >> 6] = s;
  __syncthreads();
  if (t == 0) bn[blockIdx.y * 256 + c] = wsum[0] + wsum[1] + wsum[2] + wsum[3];
}

// ---------------- BN normalize (layers 3-6 outputs only) ----------------

__global__ __launch_bounds__(256) void norm_kernel(
    const float* __restrict__ aBase, size_t aStride, const float* __restrict__ bnAll,
    const float* __restrict__ gammaAll, const float* __restrict__ betaAll,
    float* __restrict__ oBase, size_t oStride, int layer0) {
  int layer = layer0 + blockIdx.y;
  const float* a = aBase + (size_t)blockIdx.y * aStride;
  const float* bn = bnAll + blockIdx.y * 256;
  const float* gamma = gammaAll + layer * 128;
  const float* beta = betaAll + layer * 128;
  float* o = oBase + (size_t)blockIdx.y * oStride;
  int i = blockIdx.x * 256 + threadIdx.x;
  int f = (i & 31) * 4;
  const float inv = 1.f / (float)NN;
  float4 v = ((const float4*)a)[i];
  float r[4] = {v.x, v.y, v.z, v.w};
  #pragma unroll
  for (int j = 0; j < 4; j++) {
    float mean = bn[f + j] * inv;
    float var = bn[128 + f + j] * inv - mean * mean;
    float sc = gamma[f + j] * rsqrtf(var + BN_EPS);
    r[j] = (r[j] - mean) * sc + beta[f + j];
  }
  float4 ov; ov.x = r[0]; ov.y = r[1]; ov.z = r[2]; ov.w = r[3];
  ((float4*)o)[i] = ov;
}

// ---------------- host ----------------

extern "C" void kernel_launch(void* const* d_in, const int* in_sizes, int n_in,
                              void* d_out, int out_size, void* d_ws, size_t ws_size,
                              hipStream_t stream) {
  const float* x_in = (const float*)d_in[0];
  const int* ei = (const int*)d_in[1];
  const float* W1g = (const float*)d_in[3];
  const float* b1g = (const float*)d_in[4];
  const float* W2g = (const float*)d_in[5];
  const float* b2g = (const float*)d_in[6];
  const float* gg = (const float*)d_in[7];
  const float* bg = (const float*)d_in[8];
  float* out = (float*)d_out;

  char* ws = (char*)d_ws;
  const size_t OFF_AGG = 0;                  // 25,600,000 B
  const size_t OFF_X = 25600000;             // 25,600,000 B
  const size_t OFF_WB = 51200000;            // 458,752 B
  const size_t OFF_BN = 51658752;            // 4,096 B (4 layer slots)
  const size_t OFF_DEG = 51662848;           // 200,000 B
  const size_t OFF_ROW = 51862848;           // 200,004 B
  const size_t OFF_CUR = 52062852;           // 200,000 B
  const size_t OFF_ESR = 52262852;           // 2,400,000 B
  const size_t OFF_PART = 54662852;          // 4 * PART_SLOT * 4 B = 3,203,072 B

  float* agg = (float*)(ws + OFF_AGG);
  float* X = (float*)(ws + OFF_X);
  unsigned short* wb = (unsigned short*)(ws + OFF_WB);
  float* bn = (float*)(ws + OFF_BN);
  int* deg = (int*)(ws + OFF_DEG);
  int* rowp = (int*)(ws + OFF_ROW);
  int* cur = (int*)(ws + OFF_CUR);
  int* esrc = (int*)(ws + OFF_ESR);
  float* part = (float*)(ws + OFF_PART);
  // scan temporaries live inside the part region (consumed before any mlp writes part)
  int* rowl = (int*)(ws + OFF_PART);               // 200,000 B
  int* bsum = (int*)(ws + OFF_PART + 800000);      // 196 B
  int* boff = (int*)(ws + OFF_PART + 800256);      // 256 B

  // CSR build (graph is static per call; rebuilt each call per harness rules)
  hipMemsetAsync(deg, 0, NN * sizeof(int), stream);
  hist_kernel<<<(NE + 255) / 256, 256, 0, stream>>>(ei, deg);
  scan_part<<<49, 256, 0, stream>>>(deg, rowl, bsum);
  scan_top<<<1, 64, 0, stream>>>(bsum, boff, rowp);
  scan_apply<<<196, 256, 0, stream>>>(rowl, boff, rowp, cur);
  bucket_kernel<<<(NE + 255) / 256, 256, 0, stream>>>(ei, cur, esrc);
  convw_kernel<<<(NLAYERS * 16384 + 255) / 256, 256, 0, stream>>>(W1g, W2g, wb);

  // layers 0..2: act_raw kept in X (in-place), BN folded into next consumer
  for (int i = 0; i < 3; i++) {
    const float* xi = (i == 0) ? x_in : X;
    gather_kernel<<<(NN * 64 + 255) / 256, 256, 0, stream>>>(xi, esrc, rowp, agg);
    if (i == 0) {
      mlp_kernel<<<dim3(GB, 1), 256, 0, stream>>>(xi, agg, wb, b1g, b2g, X, 0, part, 0,
                                                  bn, gg, bg, deg, 0);
    } else {
      mlp_kernel<<<dim3(GB, 1), 256, 0, stream>>>(xi, agg, wb, b1g, b2g, X, 0, part, i,
                                                  bn + (i - 1) * 256, gg + (i - 1) * 128,
                                                  bg + (i - 1) * 128, deg, 1);
    }
    reduce_kernel<<<dim3(256, 1), 256, 0, stream>>>(part, bn + i * 256);
  }
  // layers 3..6 share raw X -> one gather, batched mlp (grid.y=4) writing raw act into out
  gather_kernel<<<(NN * 64 + 255) / 256, 256, 0, stream>>>(X, esrc, rowp, agg);
  mlp_kernel<<<dim3(GB, 4), 256, 0, stream>>>(X, agg, wb, b1g, b2g, out,
                                              (size_t)NN * DIM, part, 3,
                                              bn + 2 * 256, gg + 2 * 128, bg + 2 * 128,
                                              deg, 1);
  reduce_kernel<<<dim3(256, 4), 256, 0, stream>>>(part, bn);
  norm_kernel<<<dim3(NN * DIM / 4 / 256, 4), 256, 0, stream>>>(
      out, (size_t)NN * DIM, bn, gg, bg, out, (size_t)NN * DIM, 3);
}

// Round 5
// 516.609 us; speedup vs baseline: 3.1205x; 1.1640x over previous
//
#include <hip/hip_runtime.h>
#include <math.h>

#define NN 50000
#define NE 600000
#define DIM 128
#define NLAYERS 7
#define LDK 136           // padded LDS row stride in shorts (272B = 17*16B, keeps uint4 aligned)
#define BN_EPS 1e-5f
#define GB 782            // mlp blocks per layer (ceil(50000/64))
#define PART_SLOT 200192  // GB*256 floats per layer slot

typedef __attribute__((ext_vector_type(4))) float floatx4;
typedef __attribute__((ext_vector_type(8))) _Float16 half8;
typedef __attribute__((ext_vector_type(2))) _Float16 half2v;

__device__ __forceinline__ unsigned short f2h(float f) {
  _Float16 h = (_Float16)f;  // v_cvt_f16_f32, RTNE
  return __builtin_bit_cast(unsigned short, h);
}
__device__ __forceinline__ float2 up(unsigned int u) {
  half2v h = __builtin_bit_cast(half2v, u);
  return make_float2((float)h.x, (float)h.y);
}
__device__ __forceinline__ unsigned int pk(float a, float b) {
  half2v h;
  h.x = (_Float16)a;
  h.y = (_Float16)b;
  return __builtin_bit_cast(unsigned int, h);
}

// ---------------- CSR build ----------------

__global__ void hist_kernel(const int* __restrict__ ei, int* __restrict__ deg) {
  int e = blockIdx.x * 256 + threadIdx.x;
  if (e < NE) atomicAdd(&deg[ei[NE + e]], 1);
}

__global__ __launch_bounds__(256) void scan_part(const int* __restrict__ deg,
                                                 int* __restrict__ rowl,
                                                 int* __restrict__ bsum) {
  int b = blockIdx.x, t = threadIdx.x;
  int base = b * 1024 + t * 4;
  int d[4];
  #pragma unroll
  for (int j = 0; j < 4; j++) d[j] = (base + j < NN) ? deg[base + j] : 0;
  int s = d[0] + d[1] + d[2] + d[3];
  int lane = t & 63;
  int incl = s;
  #pragma unroll
  for (int off = 1; off < 64; off <<= 1) {
    int n = __shfl_up(incl, off);
    if (lane >= off) incl += n;
  }
  __shared__ int wtot[4];
  if (lane == 63) wtot[t >> 6] = incl;
  __syncthreads();
  int woff = 0;
  for (int w = 0; w < (t >> 6); w++) woff += wtot[w];
  int run = woff + incl - s;
  #pragma unroll
  for (int j = 0; j < 4; j++) {
    if (base + j < NN) rowl[base + j] = run;
    run += d[j];
  }
  if (t == 255) bsum[b] = woff + incl;
}

__global__ void scan_top(const int* __restrict__ bsum, int* __restrict__ boff,
                         int* __restrict__ row) {
  int t = threadIdx.x;  // one wave
  int v = (t < 49) ? bsum[t] : 0;
  int incl = v;
  #pragma unroll
  for (int off = 1; off < 64; off <<= 1) {
    int n = __shfl_up(incl, off);
    if (t >= off) incl += n;
  }
  if (t < 49) boff[t] = incl - v;
  if (t == 48) row[NN] = incl;
}

__global__ __launch_bounds__(256) void scan_apply(const int* __restrict__ rowl,
                                                  const int* __restrict__ boff,
                                                  int* __restrict__ row,
                                                  int* __restrict__ cur) {
  int i = blockIdx.x * 256 + threadIdx.x;
  if (i < NN) {
    int r = rowl[i] + boff[i >> 10];
    row[i] = r;
    cur[i] = r;
  }
}

__global__ void bucket_kernel(const int* __restrict__ ei, int* __restrict__ cur,
                              int* __restrict__ esrc) {
  int e = blockIdx.x * 256 + threadIdx.x;
  if (e < NE) {
    int d = ei[NE + e];
    int p = atomicAdd(&cur[d], 1);
    esrc[p] = ei[e];
  }
}

// ---------------- converts ----------------

__global__ void convw_kernel(const float* __restrict__ W1, const float* __restrict__ W2,
                             unsigned short* __restrict__ wb) {
  int i = blockIdx.x * 256 + threadIdx.x;  // 7*16384
  if (i >= NLAYERS * 16384) return;
  int l = i >> 14;
  int r = i & 16383;
  int n = r >> 7;
  int k = r & 127;
  wb[(size_t)(l * 2 + 0) * 16384 + n * 128 + k] = f2h(W1[(size_t)l * 16384 + k * 128 + n]);
  wb[(size_t)(l * 2 + 1) * 16384 + n * 128 + k] = f2h(W2[(size_t)l * 16384 + k * 128 + n]);
}

__global__ __launch_bounds__(256) void convx_kernel(const float* __restrict__ x,
                                                    unsigned int* __restrict__ x16) {
  int i = blockIdx.x * 256 + threadIdx.x;  // 1.6M exact
  float4 v = ((const float4*)x)[i];
  uint2 o;
  o.x = pk(v.x, v.y);
  o.y = pk(v.z, v.w);
  ((uint2*)x16)[i] = o;
}

// ---------------- gather (fp16): agg16[n] = sum_{e in CSR[n]} x16[esrc[e]] ----------------

__global__ __launch_bounds__(256) void gather_kernel(
    const unsigned int* __restrict__ x16, const int* __restrict__ esrc,
    const int* __restrict__ row, unsigned int* __restrict__ agg16) {
  int w = (blockIdx.x * 256 + threadIdx.x) >> 6;  // one wave per node
  int lane = threadIdx.x & 63;
  if (w >= NN) return;
  int s0 = row[w], s1 = row[w + 1];
  float ax = 0.f, ay = 0.f;
  int e = s0;
  for (; e + 3 < s1; e += 4) {
    int i0 = esrc[e], i1 = esrc[e + 1], i2 = esrc[e + 2], i3 = esrc[e + 3];
    unsigned int v0 = x16[i0 * 64 + lane];
    unsigned int v1 = x16[i1 * 64 + lane];
    unsigned int v2 = x16[i2 * 64 + lane];
    unsigned int v3 = x16[i3 * 64 + lane];
    float2 f0 = up(v0), f1 = up(v1), f2 = up(v2), f3 = up(v3);
    ax += (f0.x + f1.x) + (f2.x + f3.x);
    ay += (f0.y + f1.y) + (f2.y + f3.y);
  }
  for (; e < s1; e++) {
    float2 f = up(x16[esrc[e] * 64 + lane]);
    ax += f.x;
    ay += f.y;
  }
  agg16[w * 64 + lane] = pk(ax, ay);
}

// ---------------- single-layer MLP (layers 0-2), fp16 in/out, BN-prev folded ----------------

__global__ __launch_bounds__(256) void mlp1_kernel(
    const unsigned int* __restrict__ x16, const unsigned int* __restrict__ agg16,
    const unsigned short* __restrict__ wb,  // this layer's [2][128][128] fp16 [n][k]
    const float* __restrict__ b1, const float* __restrict__ b2,
    unsigned short* __restrict__ xout16, float* __restrict__ part,
    const float* __restrict__ bnPrev, const float* __restrict__ gPrev,
    const float* __restrict__ btPrev, const int* __restrict__ deg, int hasPrev) {
  __shared__ unsigned short hS[64 * LDK];
  __shared__ unsigned short wS[128 * LDK];
  __shared__ float scshS[256];
  int tid = threadIdx.x;
  int row0 = blockIdx.x * 64;

  if (tid < 128) {
    float sc = 1.f, sh = 0.f;
    if (hasPrev) {
      const float inv = 1.f / (float)NN;
      float mean = bnPrev[tid] * inv;
      float var = bnPrev[128 + tid] * inv - mean * mean;
      sc = gPrev[tid] * rsqrtf(var + BN_EPS);
      sh = btPrev[tid] - mean * sc;
    }
    scshS[tid] = sc;
    scshS[128 + tid] = sh;
  }
  __syncthreads();

  // stage h = sc*(x+agg) + (1+deg)*sh -> fp16 LDS, 16B/thread
  for (int idx = tid; idx < 1024; idx += 256) {
    int r = idx >> 4;
    int c = (idx & 15) * 8;  // half index
    uint4 hv = {0u, 0u, 0u, 0u};
    if (row0 + r < NN) {
      size_t base = (size_t)(row0 + r) * 16 + (c >> 3);
      uint4 xv = ((const uint4*)x16)[base];
      uint4 av = ((const uint4*)agg16)[base];
      float dr = 1.f + (float)deg[row0 + r];
      unsigned int xs[4] = {xv.x, xv.y, xv.z, xv.w};
      unsigned int as_[4] = {av.x, av.y, av.z, av.w};
      unsigned int hs[4];
      #pragma unroll
      for (int j = 0; j < 4; j++) {
        float2 xf = up(xs[j]);
        float2 af = up(as_[j]);
        int cc = c + j * 2;
        float h0 = scshS[cc] * (xf.x + af.x) + dr * scshS[128 + cc];
        float h1 = scshS[cc + 1] * (xf.y + af.y) + dr * scshS[128 + cc + 1];
        hs[j] = pk(h0, h1);
      }
      hv.x = hs[0]; hv.y = hs[1]; hv.z = hs[2]; hv.w = hs[3];
    }
    *(uint4*)&hS[r * LDK + c] = hv;
  }
  for (int q = tid; q < 2048; q += 256) {
    int rw = q >> 4;
    int c8 = (q & 15) * 8;
    *(uint4*)&wS[rw * LDK + c8] = *(const uint4*)(wb + rw * 128 + c8);
  }
  __syncthreads();

  int lane = tid & 63;
  int wav = tid >> 6;
  int quad = lane >> 4;
  int lm = lane & 15;
  int mrow = wav * 16 + lm;

  floatx4 acc[8];
  #pragma unroll
  for (int nt = 0; nt < 8; nt++) {
    floatx4 c = {0.f, 0.f, 0.f, 0.f};
    #pragma unroll
    for (int ks = 0; ks < 4; ks++) {
      half8 af = *(half8*)&hS[mrow * LDK + ks * 32 + quad * 8];
      half8 bf = *(half8*)&wS[(nt * 16 + lm) * LDK + ks * 32 + quad * 8];
      c = __builtin_amdgcn_mfma_f32_16x16x32_f16(af, bf, c, 0, 0, 0);
    }
    acc[nt] = c;
  }
  #pragma unroll
  for (int nt = 0; nt < 8; nt++) {
    float bv = b1[nt * 16 + lm];
    #pragma unroll
    for (int rg = 0; rg < 4; rg++) {
      float v = acc[nt][rg] + bv;
      v = v > 0.f ? v : 0.f;
      hS[(wav * 16 + quad * 4 + rg) * LDK + nt * 16 + lm] = f2h(v);
    }
  }
  __syncthreads();
  for (int q = tid; q < 2048; q += 256) {
    int rw = q >> 4;
    int c8 = (q & 15) * 8;
    *(uint4*)&wS[rw * LDK + c8] = *(const uint4*)(wb + 16384 + rw * 128 + c8);
  }
  __syncthreads();

  bool wvalid = (row0 + wav * 16) < NN;
  float sArr[8], sqArr[8];
  #pragma unroll
  for (int nt = 0; nt < 8; nt++) {
    floatx4 c = {0.f, 0.f, 0.f, 0.f};
    #pragma unroll
    for (int ks = 0; ks < 4; ks++) {
      half8 af = *(half8*)&hS[mrow * LDK + ks * 32 + quad * 8];
      half8 bf = *(half8*)&wS[(nt * 16 + lm) * LDK + ks * 32 + quad * 8];
      c = __builtin_amdgcn_mfma_f32_16x16x32_f16(af, bf, c, 0, 0, 0);
    }
    float bv = b2[nt * 16 + lm];
    float s = 0.f, sq = 0.f;
    #pragma unroll
    for (int rg = 0; rg < 4; rg++) {
      float v = c[rg] + bv;
      v = v > 0.f ? v : 0.f;
      if (wvalid)
        xout16[(size_t)(row0 + wav * 16 + quad * 4 + rg) * DIM + nt * 16 + lm] = f2h(v);
      s += v;
      sq += v * v;
    }
    s += __shfl_xor(s, 16);
    s += __shfl_xor(s, 32);
    sq += __shfl_xor(sq, 16);
    sq += __shfl_xor(sq, 32);
    sArr[nt] = s;
    sqArr[nt] = sq;
  }
  __syncthreads();
  float* redS = (float*)hS;
  if (quad == 0) {
    #pragma unroll
    for (int nt = 0; nt < 8; nt++) {
      redS[wav * 256 + nt * 16 + lm] = wvalid ? sArr[nt] : 0.f;
      redS[wav * 256 + 128 + nt * 16 + lm] = wvalid ? sqArr[nt] : 0.f;
    }
  }
  __syncthreads();
  float v = redS[tid] + redS[256 + tid] + redS[512 + tid] + redS[768 + tid];
  part[(size_t)blockIdx.x * 256 + tid] = v;
}

// ---------------- fused 4-layer MLP (layers 3-6): h staged once, A-frags in regs ----------------

__global__ __launch_bounds__(256) void mlp4_kernel(
    const unsigned int* __restrict__ x16, const unsigned int* __restrict__ agg16,
    const unsigned short* __restrict__ wbg,
    const float* __restrict__ b1g, const float* __restrict__ b2g,
    float* __restrict__ out, float* __restrict__ partBase,
    const float* __restrict__ bnPrev, const float* __restrict__ gPrev,
    const float* __restrict__ btPrev, const int* __restrict__ deg) {
  __shared__ unsigned short hS[64 * LDK];
  __shared__ unsigned short wS[128 * LDK];
  __shared__ float scshS[256];
  int tid = threadIdx.x;
  int row0 = blockIdx.x * 64;

  if (tid < 128) {
    const float inv = 1.f / (float)NN;
    float mean = bnPrev[tid] * inv;
    float var = bnPrev[128 + tid] * inv - mean * mean;
    float sc = gPrev[tid] * rsqrtf(var + BN_EPS);
    scshS[tid] = sc;
    scshS[128 + tid] = btPrev[tid] - mean * sc;
  }
  __syncthreads();

  for (int idx = tid; idx < 1024; idx += 256) {
    int r = idx >> 4;
    int c = (idx & 15) * 8;
    uint4 hv = {0u, 0u, 0u, 0u};
    if (row0 + r < NN) {
      size_t base = (size_t)(row0 + r) * 16 + (c >> 3);
      uint4 xv = ((const uint4*)x16)[base];
      uint4 av = ((const uint4*)agg16)[base];
      float dr = 1.f + (float)deg[row0 + r];
      unsigned int xs[4] = {xv.x, xv.y, xv.z, xv.w};
      unsigned int as_[4] = {av.x, av.y, av.z, av.w};
      unsigned int hs[4];
      #pragma unroll
      for (int j = 0; j < 4; j++) {
        float2 xf = up(xs[j]);
        float2 af = up(as_[j]);
        int cc = c + j * 2;
        float h0 = scshS[cc] * (xf.x + af.x) + dr * scshS[128 + cc];
        float h1 = scshS[cc + 1] * (xf.y + af.y) + dr * scshS[128 + cc + 1];
        hs[j] = pk(h0, h1);
      }
      hv.x = hs[0]; hv.y = hs[1]; hv.z = hs[2]; hv.w = hs[3];
    }
    *(uint4*)&hS[r * LDK + c] = hv;
  }
  __syncthreads();

  int lane = tid & 63;
  int wav = tid >> 6;
  int quad = lane >> 4;
  int lm = lane & 15;
  int mrow = wav * 16 + lm;
  bool wvalid = (row0 + wav * 16) < NN;

  // A-fragments of h live in registers across all 4 layers
  half8 aF[4];
  #pragma unroll
  for (int ks = 0; ks < 4; ks++)
    aF[ks] = *(half8*)&hS[mrow * LDK + ks * 32 + quad * 8];

  #pragma unroll 1
  for (int ly = 0; ly < 4; ly++) {
    int layer = 3 + ly;
    const unsigned short* wb = wbg + (size_t)layer * 2 * 16384;
    const float* b1 = b1g + layer * 128;
    const float* b2 = b2g + layer * 128;
    float* act = out + (size_t)ly * NN * DIM;
    float* part = partBase + (size_t)ly * PART_SLOT;

    __syncthreads();  // prev iter's wS reads + redS reads done
    for (int q = tid; q < 2048; q += 256) {
      int rw = q >> 4;
      int c8 = (q & 15) * 8;
      *(uint4*)&wS[rw * LDK + c8] = *(const uint4*)(wb + rw * 128 + c8);
    }
    __syncthreads();

    floatx4 acc[8];
    #pragma unroll
    for (int nt = 0; nt < 8; nt++) {
      floatx4 c = {0.f, 0.f, 0.f, 0.f};
      #pragma unroll
      for (int ks = 0; ks < 4; ks++) {
        half8 bf = *(half8*)&wS[(nt * 16 + lm) * LDK + ks * 32 + quad * 8];
        c = __builtin_amdgcn_mfma_f32_16x16x32_f16(aF[ks], bf, c, 0, 0, 0);
      }
      acc[nt] = c;
    }
    #pragma unroll
    for (int nt = 0; nt < 8; nt++) {
      float bv = b1[nt * 16 + lm];
      #pragma unroll
      for (int rg = 0; rg < 4; rg++) {
        float v = acc[nt][rg] + bv;
        v = v > 0.f ? v : 0.f;
        hS[(wav * 16 + quad * 4 + rg) * LDK + nt * 16 + lm] = f2h(v);
      }
    }
    __syncthreads();
    for (int q = tid; q < 2048; q += 256) {
      int rw = q >> 4;
      int c8 = (q & 15) * 8;
      *(uint4*)&wS[rw * LDK + c8] = *(const uint4*)(wb + 16384 + rw * 128 + c8);
    }
    __syncthreads();

    float sArr[8], sqArr[8];
    #pragma unroll
    for (int nt = 0; nt < 8; nt++) {
      floatx4 c = {0.f, 0.f, 0.f, 0.f};
      #pragma unroll
      for (int ks = 0; ks < 4; ks++) {
        half8 af = *(half8*)&hS[mrow * LDK + ks * 32 + quad * 8];
        half8 bf = *(half8*)&wS[(nt * 16 + lm) * LDK + ks * 32 + quad * 8];
        c = __builtin_amdgcn_mfma_f32_16x16x32_f16(af, bf, c, 0, 0, 0);
      }
      float bv = b2[nt * 16 + lm];
      float s = 0.f, sq = 0.f;
      #pragma unroll
      for (int rg = 0; rg < 4; rg++) {
        float v = c[rg] + bv;
        v = tanhf(v);
        if (wvalid)
          act[(size_t)(row0 + wav * 16 + quad * 4 + rg) * DIM + nt * 16 + lm] = v;
        s += v;
        sq += v * v;
      }
      s += __shfl_xor(s, 16);
      s += __shfl_xor(s, 32);
      sq += __shfl_xor(sq, 16);
      sq += __shfl_xor(sq, 32);
      sArr[nt] = s;
      sqArr[nt] = sq;
    }
    __syncthreads();
    float* redS = (float*)hS;
    if (quad == 0) {
      #pragma unroll
      for (int nt = 0; nt < 8; nt++) {
        redS[wav * 256 + nt * 16 + lm] = wvalid ? sArr[nt] : 0.f;
        redS[wav * 256 + 128 + nt * 16 + lm] = wvalid ? sqArr[nt] : 0.f;
      }
    }
    __syncthreads();
    float v = redS[tid] + redS[256 + tid] + redS[512 + tid] + redS[768 + tid];
    part[(size_t)blockIdx.x * 256 + tid] = v;
  }
}

// ---------------- fold per-block partials -> bn[256] per layer slot ----------------

__global__ __launch_bounds__(256) void reduce_kernel(const float* __restrict__ part,
                                                     float* __restrict__ bn) {
  int c = blockIdx.x;
  int t = threadIdx.x;
  const float* p = part + (size_t)blockIdx.y * PART_SLOT + c;
  float s = 0.f;
  for (int b = t; b < GB; b += 256) s += p[(size_t)b * 256];
  #pragma unroll
  for (int off = 1; off < 64; off <<= 1) s += __shfl_xor(s, off);
  __shared__ float wsum[4];
  if ((t & 63) == 0) wsum[t >> 6] = s;
  __syncthreads();
  if (t == 0) bn[blockIdx.y * 256 + c] = wsum[0] + wsum[1] + wsum[2] + wsum[3];
}

// ---------------- BN normalize (layers 3-6 outputs, in place) ----------------

__global__ __launch_bounds__(256) void norm_kernel(
    const float* __restrict__ aBase, const float* __restrict__ bnAll,
    const float* __restrict__ gammaAll, const float* __restrict__ betaAll,
    float* __restrict__ oBase, int layer0) {
  int layer = layer0 + blockIdx.y;
  const float* a = aBase + (size_t)blockIdx.y * NN * DIM;
  const float* bn = bnAll + blockIdx.y * 256;
  const float* gamma = gammaAll + layer * 128;
  const float* beta = betaAll + layer * 128;
  float* o = oBase + (size_t)blockIdx.y * NN * DIM;
  int i = blockIdx.x * 256 + threadIdx.x;
  int f = (i & 31) * 4;
  const float inv = 1.f / (float)NN;
  float4 v = ((const float4*)a)[i];
  float r[4] = {v.x, v.y, v.z, v.w};
  #pragma unroll
  for (int j = 0; j < 4; j++) {
    float mean = bn[f + j] * inv;
    float var = bn[128 + f + j] * inv - mean * mean;
    float sc = gamma[f + j] * rsqrtf(var + BN_EPS);
    r[j] = (r[j] - mean) * sc + beta[f + j];
  }
  float4 ov; ov.x = r[0]; ov.y = r[1]; ov.z = r[2]; ov.w = r[3];
  ((float4*)o)[i] = ov;
}

// ---------------- host ----------------

extern "C" void kernel_launch(void* const* d_in, const int* in_sizes, int n_in,
                              void* d_out, int out_size, void* d_ws, size_t ws_size,
                              hipStream_t stream) {
  const float* x_in = (const float*)d_in[0];
  const int* ei = (const int*)d_in[1];
  const float* W1g = (const float*)d_in[3];
  const float* b1g = (const float*)d_in[4];
  const float* W2g = (const float*)d_in[5];
  const float* b2g = (const float*)d_in[6];
  const float* gg = (const float*)d_in[7];
  const float* bg = (const float*)d_in[8];
  float* out = (float*)d_out;

  char* ws = (char*)d_ws;
  const size_t OFF_X16 = 0;                  // 12,800,000 B
  const size_t OFF_A16 = 12800000;           // 12,800,000 B
  const size_t OFF_WB = 25600000;            // 458,752 B
  const size_t OFF_BN = 26058752;            // 4,096 B
  const size_t OFF_DEG = 26062848;           // 200,000 B
  const size_t OFF_ROW = 26262848;           // 200,004 B
  const size_t OFF_CUR = 26462852;           // 200,000 B
  const size_t OFF_ESR = 26662852;           // 2,400,000 B
  const size_t OFF_PART = 29062852;          // 4 * PART_SLOT * 4 B

  unsigned int* X16 = (unsigned int*)(ws + OFF_X16);
  unsigned int* A16 = (unsigned int*)(ws + OFF_A16);
  unsigned short* wb = (unsigned short*)(ws + OFF_WB);
  float* bn = (float*)(ws + OFF_BN);
  int* deg = (int*)(ws + OFF_DEG);
  int* rowp = (int*)(ws + OFF_ROW);
  int* cur = (int*)(ws + OFF_CUR);
  int* esrc = (int*)(ws + OFF_ESR);
  float* part = (float*)(ws + OFF_PART);
  // scan temporaries inside part region (consumed before mlp writes part)
  int* rowl = (int*)(ws + OFF_PART);
  int* bsum = (int*)(ws + OFF_PART + 800000);
  int* boff = (int*)(ws + OFF_PART + 800256);

  hipMemsetAsync(deg, 0, NN * sizeof(int), stream);
  hist_kernel<<<(NE + 255) / 256, 256, 0, stream>>>(ei, deg);
  scan_part<<<49, 256, 0, stream>>>(deg, rowl, bsum);
  scan_top<<<1, 64, 0, stream>>>(bsum, boff, rowp);
  scan_apply<<<196, 256, 0, stream>>>(rowl, boff, rowp, cur);
  bucket_kernel<<<(NE + 255) / 256, 256, 0, stream>>>(ei, cur, esrc);
  convw_kernel<<<(NLAYERS * 16384 + 255) / 256, 256, 0, stream>>>(W1g, W2g, wb);
  convx_kernel<<<NN * DIM / 4 / 256, 256, 0, stream>>>(x_in, X16);

  // layers 0..2: fp16 X updated in place (gather consumed it into A16 first)
  for (int i = 0; i < 3; i++) {
    gather_kernel<<<(NN * 64 + 255) / 256, 256, 0, stream>>>(X16, esrc, rowp, A16);
    mlp1_kernel<<<GB, 256, 0, stream>>>(
        X16, A16, wb + (size_t)i * 2 * 16384, b1g + i * 128, b2g + i * 128,
        (unsigned short*)X16, part,
        (i == 0) ? bn : bn + (i - 1) * 256,
        (i == 0) ? gg : gg + (i - 1) * 128,
        (i == 0) ? bg : bg + (i - 1) * 128, deg, i > 0 ? 1 : 0);
    reduce_kernel<<<dim3(256, 1), 256, 0, stream>>>(part, bn + i * 256);
  }
  // layers 3..6: one gather + one fused 4-layer kernel
  gather_kernel<<<(NN * 64 + 255) / 256, 256, 0, stream>>>(X16, esrc, rowp, A16);
  mlp4_kernel<<<GB, 256, 0, stream>>>(X16, A16, wb, b1g, b2g, out, part,
                                      bn + 2 * 256, gg + 2 * 128, bg + 2 * 128, deg);
  reduce_kernel<<<dim3(256, 4), 256, 0, stream>>>(part, bn);
  norm_kernel<<<dim3(NN * DIM / 4 / 256, 4), 256, 0, stream>>>(out, bn, gg, bg, out, 3);
}